// Round 1
// baseline (621.982 us; speedup 1.0000x reference)
//
#include <hip/hip_runtime.h>
#include <hip/hip_bf16.h>

// ---------------- problem constants ----------------
#define BATCH 16
#define CI    512
#define CO    512
#define IMG   64      // H = W
#define HP    66      // padded H/W
#define NPIX  4096    // IMG*IMG
#define NTAP  9

typedef __bf16  bf16x8  __attribute__((ext_vector_type(8)));
typedef float   floatx4 __attribute__((ext_vector_type(4)));

// ---------------- workspace layout (bytes) ----------------
// s        : 16*512 f32            =    32768   @ 0
// sigma    : 16*512 f32            =    32768   @ 32768
// wsq      : 512*512 f32           =  1048576   @ 65536
// wbf      : 9*512*512 bf16        =  4718592   @ 1114112
// xpad     : 16*66*66*512 bf16     = 71368704   @ 5832704
#define OFF_S     0u
#define OFF_SIG   32768u
#define OFF_WSQ   65536u
#define OFF_WBF   1114112u
#define OFF_XPAD  5832704u
#define XPAD_BYTES 71368704u
#define WS_NEEDED (OFF_XPAD + XPAD_BYTES)

// ---------------- prep: s = style @ (affine_w/sqrt(512)).T + affine_b ----------------
__global__ void k_style(const float* __restrict__ style, const float* __restrict__ aw,
                        const float* __restrict__ ab, float* __restrict__ s_out)
{
    __shared__ float st[512];
    int b = blockIdx.x;
    int t = threadIdx.x;
    st[t]       = style[b * 512 + t];
    st[t + 256] = style[b * 512 + t + 256];
    __syncthreads();
    int i = blockIdx.y * 256 + t;
    const float4* awr = (const float4*)(aw + (size_t)i * 512);
    float sum = 0.f;
#pragma unroll 8
    for (int k = 0; k < 128; ++k) {
        float4 v = awr[k];
        sum += v.x * st[4 * k] + v.y * st[4 * k + 1] + v.z * st[4 * k + 2] + v.w * st[4 * k + 3];
    }
    s_out[b * 512 + i] = sum * 0.04419417382415922f + ab[i];
}

// ---------------- prep: wsq[o,i] = sum_t w^2, wbf[tap][o][ci] = bf16(w) ----------------
__global__ void k_wprep(const float* __restrict__ wgt, float* __restrict__ wsq,
                        unsigned short* __restrict__ wbf)
{
    int idx = blockIdx.x * 256 + threadIdx.x;   // 0 .. 262143 == o*512+ci
    const float* p = wgt + (size_t)idx * 9;
    float q = 0.f;
#pragma unroll
    for (int t9 = 0; t9 < 9; ++t9) {
        float v = p[t9];
        q += v * v;
        __hip_bfloat16 hv = __float2bfloat16(v);
        wbf[t9 * 262144 + idx] = *(unsigned short*)&hv;
    }
    wsq[idx] = q;
}

// ---------------- prep: sigma_inv[b,o] = rsqrt(sum_i wsq[o,i]*s[b,i]^2 + eps) ----------------
__global__ void k_sigma(const float* __restrict__ s_in, const float* __restrict__ wsq,
                        float* __restrict__ sig)
{
    __shared__ float s2[512];
    int b = blockIdx.x, t = threadIdx.x;
    float a0 = s_in[b * 512 + t], a1 = s_in[b * 512 + t + 256];
    s2[t] = a0 * a0;
    s2[t + 256] = a1 * a1;
    __syncthreads();
    int o = blockIdx.y * 256 + t;
    const float4* wr = (const float4*)(wsq + (size_t)o * 512);
    float sum = 0.f;
#pragma unroll 8
    for (int k = 0; k < 128; ++k) {
        float4 v = wr[k];
        sum += v.x * s2[4 * k] + v.y * s2[4 * k + 1] + v.z * s2[4 * k + 2] + v.w * s2[4 * k + 3];
    }
    sig[b * 512 + o] = rsqrtf(sum + 1e-8f);
}

// ---------------- prep: xpad[b][h+1][w+1][ci] = bf16(x[b][ci][h][w] * s[b][ci]) (NHWC, zero halo) ----
__global__ void k_xmod(const float* __restrict__ x, const float* __restrict__ s_in,
                       unsigned short* __restrict__ xpad)
{
    __shared__ float tile[64][65];
    int b = blockIdx.x, h = blockIdx.y, cic = blockIdx.z;
    int t = threadIdx.x;
    int lane_w = t & 63, grp = t >> 6;
    int ci0 = cic * 64;
#pragma unroll 4
    for (int it = 0; it < 16; ++it) {
        int ci_l = grp * 16 + it;
        int ci = ci0 + ci_l;
        float v = x[(((size_t)(b * 512 + ci)) << 12) + (h << 6) + lane_w] * s_in[b * 512 + ci];
        tile[ci_l][lane_w] = v;
    }
    __syncthreads();
#pragma unroll 4
    for (int it = 0; it < 16; ++it) {
        int w_l = grp * 16 + it;
        float v = tile[lane_w][w_l];   // lane_w is the ci index here; stride-65 -> conflict-free
        __hip_bfloat16 hv = __float2bfloat16(v);
        xpad[((size_t)((b * 66 + h + 1) * 66 + (w_l + 1))) * 512 + ci0 + lane_w] = *(unsigned short*)&hv;
    }
}

// ---------------- main conv: implicit GEMM, 128x128 tile, K = 9 taps x 16 ci-chunks of 32 ----------
__device__ __forceinline__ void gload16(const void* g, void* l)
{
    __builtin_amdgcn_global_load_lds(
        (const __attribute__((address_space(1))) unsigned int*)g,
        (__attribute__((address_space(3))) unsigned int*)l, 16, 0, 0);
}

__global__ __launch_bounds__(256, 2)
void k_conv(const unsigned short* __restrict__ xpad, const unsigned short* __restrict__ wbf,
            const float* __restrict__ sig, float* __restrict__ y)
{
    __shared__ unsigned short A_lds[4096];  // [128 o][32 k] bf16, 8 KB
    __shared__ unsigned short B_lds[4096];  // [128 pix][32 k] bf16, 8 KB
    int t = threadIdx.x;
    int w = t >> 6, l = t & 63;
    int wr = w >> 1, wc = w & 1;
    int bx = blockIdx.x;
    int b = bx >> 7, rem = bx & 127;
    int co_t = rem >> 5, pix_t = rem & 31;
    int o_base = co_t << 7;     // 128 output channels per block
    int h0 = pix_t << 1;        // 2 image rows (128 pixels) per block

    const char* wb = (const char*)wbf;
    const char* xb = (const char*)xpad;

    // staging: 512 lane-loads of 16 B each for A and for B; two wave-calls each
    int idx0 = (w << 6) + l;
    int idx1 = idx0 + 256;
    int aoff0 = ((o_base + (idx0 >> 2)) << 10) + ((idx0 & 3) << 4);
    int aoff1 = ((o_base + (idx1 >> 2)) << 10) + ((idx1 & 3) << 4);
    int p0 = idx0 >> 2, p1 = idx1 >> 2;
    int boff0 = (((b * 66 + h0 + (p0 >> 6)) * 66 + (p0 & 63)) << 10) + ((idx0 & 3) << 4);
    int boff1 = (((b * 66 + h0 + (p1 >> 6)) * 66 + (p1 & 63)) << 10) + ((idx1 & 3) << 4);
    char* aL0 = (char*)A_lds + (w << 10);
    char* aL1 = (char*)A_lds + 4096 + (w << 10);
    char* bL0 = (char*)B_lds + (w << 10);
    char* bL1 = (char*)B_lds + 4096 + (w << 10);

    floatx4 acc[4][4];
#pragma unroll
    for (int i = 0; i < 4; ++i)
#pragma unroll
        for (int j = 0; j < 4; ++j)
            acc[i][j] = (floatx4){0.f, 0.f, 0.f, 0.f};

    // fragment read offsets (in shorts): row stride 32; A[m=lane&15][k=quad*8+j]
    int fa = wr * 2048 + (l & 15) * 32 + (l >> 4) * 8;
    int fb = wc * 2048 + (l & 15) * 32 + (l >> 4) * 8;

    for (int tap = 0; tap < 9; ++tap) {
        int kh = tap / 3;
        int kw = tap - kh * 3;
        int tb = (kh * 66 + kw) << 10;   // B byte shift for this tap
        int ta = tap << 19;              // A byte shift: tap * 512*512*2
        for (int cic = 0; cic < 16; ++cic) {
            int kb = cic << 6;           // 32 ci * 2 B
            gload16(wb + ta + kb + aoff0, aL0);
            gload16(wb + ta + kb + aoff1, aL1);
            gload16(xb + tb + kb + boff0, bL0);
            gload16(xb + tb + kb + boff1, bL1);
            __syncthreads();             // drains vmcnt for global_load_lds

            bf16x8 af[4], bfr[4];
#pragma unroll
            for (int i = 0; i < 4; ++i) af[i]  = *(const bf16x8*)&A_lds[fa + i * 512];
#pragma unroll
            for (int j = 0; j < 4; ++j) bfr[j] = *(const bf16x8*)&B_lds[fb + j * 512];
#pragma unroll
            for (int i = 0; i < 4; ++i)
#pragma unroll
                for (int j = 0; j < 4; ++j)
                    acc[i][j] = __builtin_amdgcn_mfma_f32_16x16x32_bf16(af[i], bfr[j], acc[i][j], 0, 0, 0);
            __syncthreads();
        }
    }

    // epilogue: C/D layout col=lane&15, row=quad*4+reg; scale by sigma_inv, store NCHW fp32
    int col = l & 15, quad = l >> 4;
    const float* sb = sig + b * 512;
#pragma unroll
    for (int i = 0; i < 4; ++i) {
        int ob = o_base + wr * 64 + i * 16 + quad * 4;
#pragma unroll
        for (int r = 0; r < 4; ++r) {
            int o = ob + r;
            float sv = sb[o];
            float* yrow = y + (((size_t)(b * 512 + o)) << 12);
#pragma unroll
            for (int j = 0; j < 4; ++j) {
                int pix = (pix_t << 7) + wc * 64 + j * 16 + col;  // == h*64 + w
                yrow[pix] = acc[i][j][r] * sv;
            }
        }
    }
}

// ---------------- launcher ----------------
extern "C" void kernel_launch(void* const* d_in, const int* in_sizes, int n_in,
                              void* d_out, int out_size, void* d_ws, size_t ws_size,
                              hipStream_t stream)
{
    const float* x        = (const float*)d_in[0];
    const float* style    = (const float*)d_in[1];
    const float* weight   = (const float*)d_in[2];
    const float* affine_w = (const float*)d_in[3];
    const float* affine_b = (const float*)d_in[4];
    float* y = (float*)d_out;

    if (ws_size < (size_t)WS_NEEDED) {
        // Workspace too small for the bf16 staging buffers; bail loudly
        // (output stays zero -> validation will flag it, telling us to restructure).
        return;
    }

    char* ws = (char*)d_ws;
    float*          s_buf = (float*)(ws + OFF_S);
    float*          sig   = (float*)(ws + OFF_SIG);
    float*          wsq   = (float*)(ws + OFF_WSQ);
    unsigned short* wbf   = (unsigned short*)(ws + OFF_WBF);
    unsigned short* xpad  = (unsigned short*)(ws + OFF_XPAD);

    hipMemsetAsync(xpad, 0, XPAD_BYTES, stream);                         // zero halo
    k_style<<<dim3(16, 2), 256, 0, stream>>>(style, affine_w, affine_b, s_buf);
    k_wprep<<<1024, 256, 0, stream>>>(weight, wsq, wbf);
    k_sigma<<<dim3(16, 2), 256, 0, stream>>>(s_buf, wsq, sig);
    k_xmod<<<dim3(16, 64, 8), 256, 0, stream>>>(x, s_buf, xpad);
    k_conv<<<2048, 256, 0, stream>>>(xpad, wbf, sig, y);
}